// Round 10
// baseline (298.356 us; speedup 1.0000x reference)
//
#include <hip/hip_runtime.h>
#include <hip/hip_fp16.h>
#include <math.h>

// ---------------------------------------------------------------------------
// 3-layer GCN. R2: bucketed CSR build. R3: fp16 gathers. R4: LDS-only CSR.
// R5: MFMA dense transforms, fp16 buffers. R6: pre-scaled g. R7: oct-per-row
// aggs. R8: unroll-4 gathers, fused prep. R9: layer-2 agg split into two
// half-feature passes. R10 (REVERTED): deep pipeline + broad nt hints.
// R11: LDS col staging in aggs; agg128 58.5->55.3us, FETCH 175->164MB.
// R12-R14 (REVERTED): per-row neighbor sort — build cost swamped ~2% agg gain.
// R15: hist+scan folded away; 317->306us. R16: GEMM coalesced epilogue +
// prep fused into build/scatter (~8us). R17: layer-1 agg fused into gemm1
// (294.8). R18: gemm2+gemm3 fused, a2 LDS-only (292.7; small — GEMMs were
// already cheap/overlapped).
// R19: DIAGNOSTIC SPLIT — agg128 launched as two half dispatches (half is a
//      kernel arg). Each half ~27us drops out of top-5, surfacing the
//      never-profiled #2..#5 kernels (~240us of runtime unaccounted by the
//      model; must see where it lives before optimizing further). Cost: one
//      launch gap. Analysis note: agg128 FETCH=164MB ≈ per-XCD compulsory
//      unique-line floor (8 XCD x 86.5% coverage x 12.8MB x 2 halves + col)
//      — fp16 gather traffic cannot go lower; service rate ~3.5TB/s.
// ---------------------------------------------------------------------------

#define THREADS 256
#define BSHIFT 8               // nodes per bucket = 256
#define BNODES (1 << BSHIFT)
#define NBUCK_MAX 512
#define EPT 16
#define CHUNK (THREADS * EPT)
#define COLCAP 4096            // LDS col slice per agg block
#define SLOTCAP 5120           // slots per bucket (avg 4096, sigma 64)

typedef _Float16 half8 __attribute__((ext_vector_type(8)));
typedef float floatx4 __attribute__((ext_vector_type(4)));

__device__ __forceinline__ float celu1(float v) {
    return v > 0.0f ? v : expm1f(v);
}

__device__ __forceinline__ void add8(float* acc, uint4 u) {
    const __half2* h2 = (const __half2*)&u;
    float2 f;
    f = __half22float2(h2[0]); acc[0] += f.x; acc[1] += f.y;
    f = __half22float2(h2[1]); acc[2] += f.x; acc[3] += f.y;
    f = __half22float2(h2[2]); acc[4] += f.x; acc[5] += f.y;
    f = __half22float2(h2[3]); acc[6] += f.x; acc[7] += f.y;
}

// ---- CSR build: slotted counting scatter (+W transpose riders) ------------

// packed edge record: (dst & (BNODES-1)) << 20 | src   (valid: N < 2^20)
__global__ __launch_bounds__(THREADS) void bucket_scatter_kernel(
    const int* __restrict__ src, const int* __restrict__ dst,
    int* __restrict__ bucketCnt, int* __restrict__ ePack2, int E, int NBUCK,
    int SB,
    const float* __restrict__ W1, __half* __restrict__ Wt1,
    const float* __restrict__ W2, __half* __restrict__ Wt2,
    const float* __restrict__ W3, __half* __restrict__ Wt3) {
    if (blockIdx.x >= SB) {   // block-uniform branch: W-transpose riders
        int b = blockIdx.x - SB;
        const float* W; __half* Wt; int K, F;
        if (b < 32)      { W = W1; Wt = Wt1; K = 64;  F = 128; }
        else if (b < 96) { W = W2; Wt = Wt2; K = 128; F = 128; b -= 32; }
        else             { W = W3; Wt = Wt3; K = 128; F = 64;  b -= 96; }
        int i = b * THREADS + threadIdx.x;
        if (i < K * F) {
            int k = i / F, f = i % F;
            Wt[f * K + k] = __float2half(W[i]);
        }
        return;
    }
    __shared__ int lcnt[NBUCK_MAX];
    __shared__ int lbase[NBUCK_MAX];
    for (int i = threadIdx.x; i < NBUCK; i += THREADS) lcnt[i] = 0;
    __syncthreads();
    const int base = blockIdx.x * CHUNK;
    int bk[EPT], rk[EPT], pk[EPT];
#pragma unroll
    for (int i = 0; i < EPT; ++i) {
        int e = base + i * THREADS + threadIdx.x;
        if (e < E) {
            int d = dst[e];
            pk[i] = ((d & (BNODES - 1)) << 20) | src[e];
            bk[i] = d >> BSHIFT;
            rk[i] = atomicAdd(&lcnt[bk[i]], 1);
        } else {
            bk[i] = -1;
        }
    }
    __syncthreads();
    for (int i = threadIdx.x; i < NBUCK; i += THREADS)
        if (lcnt[i]) lbase[i] = atomicAdd(&bucketCnt[i], lcnt[i]);
    __syncthreads();
#pragma unroll
    for (int i = 0; i < EPT; ++i) {
        if (bk[i] >= 0) {
            int slot = lbase[bk[i]] + rk[i];
            if (slot < SLOTCAP) ePack2[bk[i] * SLOTCAP + slot] = pk[i];
        }
    }
}

// one block per bucket: in-block bucket prefix -> LDS hist -> LDS scan ->
// rowptr/dinv/col -> fused xg = dinv*x fp16 conversion for this bucket's rows.
__global__ __launch_bounds__(THREADS) void build_kernel(
    const int* __restrict__ ePack2, const int* __restrict__ bucketCnt,
    int* __restrict__ rowptr, float* __restrict__ dinv,
    int* __restrict__ col, const float* __restrict__ x,
    __half* __restrict__ xg, int N, int NBUCK) {
    __shared__ int hist[BNODES];
    __shared__ int scn[BNODES];
    __shared__ int ps[2 * BNODES];
    __shared__ float dinvS[BNODES];
    const int tid = threadIdx.x;
    const int b = blockIdx.x;

    // exclusive prefix over bucketCnt[0..NBUCK) (NBUCK <= 512)
    ps[tid] = (tid < NBUCK) ? bucketCnt[tid] : 0;
    ps[tid + 256] = (tid + 256 < NBUCK) ? bucketCnt[tid + 256] : 0;
    __syncthreads();
    for (int o = 1; o < 512; o <<= 1) {
        int a = (tid >= o) ? ps[tid - o] : 0;
        int c = ps[tid + 256 - o];           // tid+256 >= o always (o <= 256)
        __syncthreads();
        if (tid >= o) ps[tid] += a;
        ps[tid + 256] += c;
        __syncthreads();
    }
    const int cntb = bucketCnt[b];
    const int off = ps[b] - cntb;            // exclusive prefix
    if (b == NBUCK - 1 && tid == 0) rowptr[N] = ps[NBUCK - 1];
    const int base = b * SLOTCAP;

    hist[tid] = 0;
    __syncthreads();
    for (int e = tid; e < cntb; e += THREADS)
        atomicAdd(&hist[((unsigned)ePack2[base + e]) >> 20], 1);
    __syncthreads();
    int deg = hist[tid];
    scn[tid] = deg;
    __syncthreads();
    for (int o = 1; o < BNODES; o <<= 1) {
        int t = 0;
        if (tid >= o) t = scn[tid - o];
        __syncthreads();
        if (tid >= o) scn[tid] += t;
        __syncthreads();
    }
    const int ex = off + scn[tid] - deg;
    const int node = (b << BSHIFT) + tid;
    float dv = rsqrtf((float)deg + 1.0f);    // +1 self-loop
    dinvS[tid] = dv;
    if (node < N) {
        rowptr[node] = ex;
        dinv[node] = dv;
    }
    scn[tid] = ex;
    __syncthreads();
    for (int e = tid; e < cntb; e += THREADS) {
        int p = ePack2[base + e];
        int pos = atomicAdd(&scn[((unsigned)p) >> 20], 1);
        col[pos] = p & 0xFFFFF;   // plain store: col re-read by aggs soon
    }

    // fused prep: xg rows of this bucket (16B units, block-strided, coalesced)
    const int rowBase = b << BSHIFT;
    int nrows = N - rowBase;
    if (nrows > BNODES) nrows = BNODES;
    if (nrows > 0) {
        const int umax = nrows * 8;          // 8 x 16B units per 64-feat row
        const floatx4* x4 = (const floatx4*)x;
        uint4* xg4 = (uint4*)xg;
        const size_t gbase = (size_t)rowBase * 8;
        for (int u = tid; u < umax; u += THREADS) {
            float d = dinvS[u >> 3];
            size_t gi = gbase + u;
            floatx4 a = __builtin_nontemporal_load(x4 + gi * 2);  // x never re-read
            floatx4 c = __builtin_nontemporal_load(x4 + gi * 2 + 1);
            __half2 h[4] = {__floats2half2_rn(a.x * d, a.y * d), __floats2half2_rn(a.z * d, a.w * d),
                            __floats2half2_rn(c.x * d, c.y * d), __floats2half2_rn(c.z * d, c.w * d)};
            xg4[gi] = *(uint4*)h;
        }
    }
}

// ---- FUSED layer-1: agg(xg) -> LDS -> MFMA -> dinv*celu(.) -> fp16 out ----
// 64 rows/block. Phase1: 32 octs aggregate rows o and o+32 into sX.
// Phase2: Wt loaded into union buffer (over dead col slice), MFMA from LDS,
// coalesced epilogue. K=64, F=128 instance used for layer 1.

template <int K, int F>
__global__ __launch_bounds__(THREADS) void agg_gemm_kernel(
    const __half* __restrict__ g, const int* __restrict__ rowptr,
    const int* __restrict__ col, const float* __restrict__ dinv,
    const float* __restrict__ bias, const __half* __restrict__ Wt,
    __half* __restrict__ outh, int N) {
    constexpr int KP = K + 8;
    constexpr int NT = F / 16;
    constexpr int FP = F + 8;
    constexpr int UNIH = (F * KP > 64 * FP) ? F * KP : 64 * FP;  // halves
    __shared__ __half uni[UNIH];          // col slice -> Ws -> epilogue buf
    __shared__ __half sX[64 * KP];        // aggregated A tile (fp16)
    __shared__ int srp[65];
    __shared__ float dinvS[64];
    int* scol = (int*)uni;
    constexpr int SCCAP = (UNIH * 2) / 4; // int capacity of uni

    const int tid = threadIdx.x;
    const int lane = tid & 63, wave = tid >> 6;
    const int sub = lane & 7;
    const int r0 = blockIdx.x * 64;

    if (tid < 65) {
        int rr = r0 + tid;
        srp[tid] = rowptr[rr > N ? N : rr];
    }
    if (tid < 64) {
        int rr = r0 + tid;
        dinvS[tid] = (rr < N) ? dinv[rr] : 0.f;
    }
    __syncthreads();
    const int eBase = srp[0], eEnd = srp[64];
    const int cnt = eEnd - eBase;
    const bool staged = (cnt <= SCCAP);
    if (staged) {
        for (int i = tid; i < cnt; i += THREADS) scol[i] = col[eBase + i];
    }
    __syncthreads();

    // ---- phase 1: aggregate 64 rows (oct handles rows o, o+32) ----
    const int o = wave * 8 + (lane >> 3);   // 0..31
    const uint4* __restrict__ g4 = (const uint4*)g + sub;  // K/8 uint4 per row
    constexpr int RU = K / 8;               // uint4 per row
#pragma unroll
    for (int hh = 0; hh < 2; ++hh) {
        const int lr = o + hh * 32;
        const int r = r0 + lr;
        const bool valid = (r < N);
        const int start = srp[lr], end = srp[lr + 1];
        float acc[8] = {0.f, 0.f, 0.f, 0.f, 0.f, 0.f, 0.f, 0.f};
        if (valid) add8(acc, g4[(size_t)r * RU]);   // self-loop
        int e = start;
        if (staged) {
            for (; e + 4 <= end; e += 4) {
                int c0 = scol[e - eBase], c1 = scol[e + 1 - eBase];
                int c2 = scol[e + 2 - eBase], c3 = scol[e + 3 - eBase];
                uint4 u0 = g4[(size_t)c0 * RU];
                uint4 u1 = g4[(size_t)c1 * RU];
                uint4 u2 = g4[(size_t)c2 * RU];
                uint4 u3 = g4[(size_t)c3 * RU];
                add8(acc, u0); add8(acc, u1); add8(acc, u2); add8(acc, u3);
            }
            for (; e < end; ++e) add8(acc, g4[(size_t)scol[e - eBase] * RU]);
        } else {
            for (; e + 4 <= end; e += 4) {
                int c0 = col[e], c1 = col[e + 1], c2 = col[e + 2], c3 = col[e + 3];
                uint4 u0 = g4[(size_t)c0 * RU];
                uint4 u1 = g4[(size_t)c1 * RU];
                uint4 u2 = g4[(size_t)c2 * RU];
                uint4 u3 = g4[(size_t)c3 * RU];
                add8(acc, u0); add8(acc, u1); add8(acc, u2); add8(acc, u3);
            }
            for (; e < end; ++e) add8(acc, g4[(size_t)col[e] * RU]);
        }
        const float dr = dinvS[lr];
        __half2 hp[4] = {__floats2half2_rn(acc[0] * dr, acc[1] * dr),
                         __floats2half2_rn(acc[2] * dr, acc[3] * dr),
                         __floats2half2_rn(acc[4] * dr, acc[5] * dr),
                         __floats2half2_rn(acc[6] * dr, acc[7] * dr)};
        *(uint4*)&sX[lr * KP + sub * 8] = *(uint4*)hp;
    }
    __syncthreads();

    // ---- load Ws over the (dead) col slice ----
    for (int i = tid; i < F * K / 8; i += THREADS) {
        int f = i / (K / 8), kg = i % (K / 8);
        *(uint4*)&uni[f * KP + kg * 8] = ((const uint4*)Wt)[i];
    }
    __syncthreads();

    // ---- phase 2: MFMA from LDS ----
    const int q = lane >> 4, mn = lane & 15;
    const int lrowA = wave * 16 + mn;       // A-fragment local row
    floatx4 acc[NT];
#pragma unroll
    for (int t = 0; t < NT; ++t) acc[t] = {0.f, 0.f, 0.f, 0.f};
#pragma unroll
    for (int k0 = 0; k0 < K; k0 += 32) {
        half8 a = *(const half8*)&sX[lrowA * KP + k0 + q * 8];
#pragma unroll
        for (int t = 0; t < NT; ++t) {
            half8 b = *(const half8*)&uni[(t * 16 + mn) * KP + k0 + q * 8];
            acc[t] = __builtin_amdgcn_mfma_f32_16x16x32_f16(a, b, acc[t], 0, 0, 0);
        }
    }

    // D: reg i <-> local row = wave*16 + q*4 + i, col = t*16 + mn
    const int lrow0 = wave * 16 + q * 4;
    float dv[4];
#pragma unroll
    for (int i = 0; i < 4; ++i) dv[i] = dinvS[lrow0 + i];
    __syncthreads();  // all waves done reading uni(Ws) + sX
#pragma unroll
    for (int t = 0; t < NT; ++t) {
        const int coln = t * 16 + mn;
        const float bv = bias[coln];
#pragma unroll
        for (int i = 0; i < 4; ++i) {
            float v = celu1(acc[t][i] + bv) * dv[i];   // ACT + SCALE (layer 1)
            uni[(lrow0 + i) * FP + coln] = __float2half(v);
        }
    }
    __syncthreads();
    // coalesced store: 64 rows x F halves, uint4 chunks, block-striped
    constexpr int CPR = F / 8;
    uint4* out4 = (uint4*)outh;
    for (int idx = tid; idx < 64 * CPR; idx += THREADS) {
        int row = idx / CPR, chunk = idx % CPR;
        int r = r0 + row;
        if (r < N) out4[(size_t)r * CPR + chunk] = *(uint4*)&uni[row * FP + chunk * 8];
    }
}

// ---- FUSED layers 2b+3a: g3 = dinv*(celu(s2@W2+b2)@W3) --------------------
// Per 64-row block: K-loop-1 (W2 in WsA, s2 nt-loaded) -> a2 into sX (LDS
// only, never global) -> W3 over dead WsA -> K-loop-2 (A = own-wave a2 rows)
// -> dinv scale -> coalesced fp16 store. Kills the 51.2MB a2 roundtrip.

__global__ __launch_bounds__(THREADS) void gemm23_kernel(
    const __half* __restrict__ X,      // s2 (FA), N x 128
    const __half* __restrict__ Wt2,    // [f][k] 128x128
    const float* __restrict__ b2,
    const __half* __restrict__ Wt3,    // [f][k] 64x128
    const float* __restrict__ dinv,
    __half* __restrict__ outh,         // g3 (FB), N x 64
    int N) {
    constexpr int K = 128;
    constexpr int KP = K + 8;          // 136
    constexpr int F2 = 128, NT2 = F2 / 16;
    constexpr int F3 = 64,  NT3 = F3 / 16;
    constexpr int FP3 = F3 + 8;        // 72 (epilogue stride; 64*FP3 < 64*KP)
    __shared__ __half WsA[F2 * KP];    // W2t, then W3t (reuse)
    __shared__ __half sX[64 * KP];     // a2 tile; reused as epilogue buffer
    __shared__ float dinvS[64];

    const int tid = threadIdx.x;
    const int wave = tid >> 6, lane = tid & 63;
    const int q = lane >> 4, mn = lane & 15;
    const int r0 = blockIdx.x * 64;

    for (int i = tid; i < F2 * K / 8; i += THREADS) {
        int f = i / (K / 8), kg = i % (K / 8);
        *(uint4*)&WsA[f * KP + kg * 8] = ((const uint4*)Wt2)[i];
    }
    if (tid < 64) {
        int rr = r0 + tid;
        dinvS[tid] = (rr < N) ? dinv[rr] : 0.f;
    }
    __syncthreads();

    int arow = r0 + wave * 16 + mn;
    if (arow >= N) arow = N - 1;       // clamp; garbage rows masked on store

    // ---- K-loop 1: acc1 = s2 @ W2 ----
    floatx4 acc1[NT2];
#pragma unroll
    for (int t = 0; t < NT2; ++t) acc1[t] = {0.f, 0.f, 0.f, 0.f};
    const __half* xp = X + (size_t)arow * K + q * 8;
#pragma unroll
    for (int k0 = 0; k0 < K; k0 += 32) {
        half8 a = __builtin_nontemporal_load((const half8*)(xp + k0));  // s2 dead after
#pragma unroll
        for (int t = 0; t < NT2; ++t) {
            half8 b = *(const half8*)&WsA[(t * 16 + mn) * KP + k0 + q * 8];
            acc1[t] = __builtin_amdgcn_mfma_f32_16x16x32_f16(a, b, acc1[t], 0, 0, 0);
        }
    }

    // ---- epilogue 1: a2 = celu(acc1 + b2) -> sX (own-wave rows) ----
    const int lrow0 = wave * 16 + q * 4;
#pragma unroll
    for (int t = 0; t < NT2; ++t) {
        const int coln = t * 16 + mn;
        const float bv = b2[coln];
#pragma unroll
        for (int i = 0; i < 4; ++i)
            sX[(lrow0 + i) * KP + coln] = __float2half(celu1(acc1[t][i] + bv));
    }
    __syncthreads();   // sX complete; WsA dead (all waves past K-loop 1)

    // ---- load W3t over WsA ----
    for (int i = tid; i < F3 * K / 8; i += THREADS) {
        int f = i / (K / 8), kg = i % (K / 8);
        *(uint4*)&WsA[f * KP + kg * 8] = ((const uint4*)Wt3)[i];
    }
    __syncthreads();

    // ---- K-loop 2: acc2 = a2 @ W3 (A = own-wave sX rows) ----
    floatx4 acc2[NT3];
#pragma unroll
    for (int t = 0; t < NT3; ++t) acc2[t] = {0.f, 0.f, 0.f, 0.f};
    const int lrowA = wave * 16 + mn;
#pragma unroll
    for (int k0 = 0; k0 < K; k0 += 32) {
        half8 a = *(const half8*)&sX[lrowA * KP + k0 + q * 8];
#pragma unroll
        for (int t = 0; t < NT3; ++t) {
            half8 b = *(const half8*)&WsA[(t * 16 + mn) * KP + k0 + q * 8];
            acc2[t] = __builtin_amdgcn_mfma_f32_16x16x32_f16(a, b, acc2[t], 0, 0, 0);
        }
    }

    float dv[4];
#pragma unroll
    for (int i = 0; i < 4; ++i) dv[i] = dinvS[lrow0 + i];
    __syncthreads();   // ALL waves done reading sX before epilogue overwrite
#pragma unroll
    for (int t = 0; t < NT3; ++t) {
        const int coln = t * 16 + mn;
#pragma unroll
        for (int i = 0; i < 4; ++i)
            sX[(lrow0 + i) * FP3 + coln] = __float2half(acc2[t][i] * dv[i]);
    }
    __syncthreads();
    // coalesced store: 64 rows x 64 halves
    constexpr int CPR = F3 / 8;
    uint4* out4 = (uint4*)outh;
    for (int idx = tid; idx < 64 * CPR; idx += THREADS) {
        int row = idx / CPR, chunk = idx % CPR;
        int r = r0 + row;
        if (r < N) out4[(size_t)r * CPR + chunk] = *(uint4*)&sX[row * FP3 + chunk * 8];
    }
}

// ---- Aggregation F=64: oct (8 lanes) per row, LDS-staged col --------------

template <bool ACT, bool OUTH>
__global__ __launch_bounds__(THREADS) void agg64g_kernel(
    const __half* __restrict__ g, const int* __restrict__ rowptr,
    const int* __restrict__ col, const float* __restrict__ dinv,
    const float* __restrict__ bias, void* __restrict__ outv, int N) {
    __shared__ int scol[COLCAP];
    __shared__ int srp[33];
    const int tid = threadIdx.x;
    const int lane = tid & 63, wave = tid >> 6;
    const int oct = lane >> 3, sub = lane & 7;
    const int r0 = blockIdx.x * 32;
    const int lr = wave * 8 + oct;
    const int r = r0 + lr;

    if (tid < 33) {
        int rr = r0 + tid;
        srp[tid] = rowptr[rr > N ? N : rr];
    }
    __syncthreads();
    const int eBase = srp[0], eEnd = srp[32];
    const int cnt = eEnd - eBase;
    const bool staged = (cnt <= COLCAP);
    if (staged) {
        for (int i = tid; i < cnt; i += THREADS) scol[i] = col[eBase + i];
    }
    __syncthreads();

    const uint4* __restrict__ g4 = (const uint4*)g + sub;  // 8 uint4 per row
    const bool valid = (r < N);
    int start = srp[lr], end = srp[lr + 1];

    float acc[8] = {0.f, 0.f, 0.f, 0.f, 0.f, 0.f, 0.f, 0.f};
    if (valid) add8(acc, g4[(size_t)r * 8]);  // self-loop

    int e = start;
#define GLOOP64(GETC)                                                     \
    for (; e + 4 <= end; e += 4) {                                        \
        int c0 = GETC(e), c1 = GETC(e + 1), c2 = GETC(e + 2), c3 = GETC(e + 3); \
        uint4 u0 = g4[(size_t)c0 * 8];                                    \
        uint4 u1 = g4[(size_t)c1 * 8];                                    \
        uint4 u2 = g4[(size_t)c2 * 8];                                    \
        uint4 u3 = g4[(size_t)c3 * 8];                                    \
        add8(acc, u0); add8(acc, u1); add8(acc, u2); add8(acc, u3);       \
    }                                                                     \
    for (; e < end; ++e) add8(acc, g4[(size_t)GETC(e) * 8]);
    if (staged) {
#define CL(i) scol[(i) - eBase]
        GLOOP64(CL)
#undef CL
    } else {
#define CG(i) col[i]
        GLOOP64(CG)
#undef CG
    }
#undef GLOOP64

    if (valid) {
        const float dr = dinv[r];
        float res[8];
#pragma unroll
        for (int k = 0; k < 8; ++k) res[k] = acc[k] * dr;
        if constexpr (ACT) {
            const float* bp = bias + sub * 8;
#pragma unroll
            for (int k = 0; k < 8; ++k) res[k] = celu1(res[k] + bp[k]);
        }
        if constexpr (OUTH) {
            __half2 hp[4] = {__floats2half2_rn(res[0], res[1]), __floats2half2_rn(res[2], res[3]),
                             __floats2half2_rn(res[4], res[5]), __floats2half2_rn(res[6], res[7])};
            *(uint4*)((__half*)outv + (size_t)r * 64 + sub * 8) = *(uint4*)hp;
        } else {
            // final layer: out never re-read -> nt stores keep table in L2
            float* o = (float*)outv + (size_t)r * 64 + sub * 8;
            floatx4 o0 = {res[0], res[1], res[2], res[3]};
            floatx4 o1 = {res[4], res[5], res[6], res[7]};
            __builtin_nontemporal_store(o0, (floatx4*)o);
            __builtin_nontemporal_store(o1, (floatx4*)o + 1);
        }
    }
}

// ---- Aggregation F=128, one half-feature pass per dispatch ----------------
// 8-lane oct per row: pass working set 12.8 MB for L2 hit rate. `half` is a
// kernel argument; the two halves are separate stream-ordered dispatches
// (R19: surfaces hidden kernels in the profile; behavior ≈ R18 block order).

__global__ __launch_bounds__(THREADS) void agg128g_kernel(
    const __half* __restrict__ g, const int* __restrict__ rowptr,
    const int* __restrict__ col, const float* __restrict__ dinv,
    __half* __restrict__ out, int N, int half) {
    __shared__ int scol[COLCAP];
    __shared__ int srp[33];
    const int tid = threadIdx.x;
    const int lane = tid & 63, wave = tid >> 6;
    const int oct = lane >> 3, sub = lane & 7;
    const int r0 = blockIdx.x * 32;
    const int lr = wave * 8 + oct;
    const int r = r0 + lr;

    if (tid < 33) {
        int rr = r0 + tid;
        srp[tid] = rowptr[rr > N ? N : rr];
    }
    __syncthreads();
    const int eBase = srp[0], eEnd = srp[32];
    const int cnt = eEnd - eBase;
    const bool staged = (cnt <= COLCAP);
    if (staged) {
        for (int i = tid; i < cnt; i += THREADS) scol[i] = col[eBase + i];
    }
    __syncthreads();

    // pre-offset by feature half + sub; row stride = 16 uint4 (128 halves)
    const uint4* __restrict__ g4 = (const uint4*)g + half * 8 + sub;
    const bool valid = (r < N);
    int start = srp[lr], end = srp[lr + 1];

    float acc[8] = {0.f, 0.f, 0.f, 0.f, 0.f, 0.f, 0.f, 0.f};
    if (valid) add8(acc, g4[(size_t)r * 16]);  // self-loop

    int e = start;
#define GLOOP128(GETC)                                                    \
    for (; e + 4 <= end; e += 4) {                                        \
        int c0 = GETC(e), c1 = GETC(e + 1), c2 = GETC(e + 2), c3 = GETC(e + 3); \
        uint4 u0 = g4[(size_t)c0 * 16];                                   \
        uint4 u1 = g4[(size_t)c1 * 16];                                   \
        uint4 u2 = g4[(size_t)c2 * 16];                                   \
        uint4 u3 = g4[(size_t)c3 * 16];                                   \
        add8(acc, u0); add8(acc, u1); add8(acc, u2); add8(acc, u3);       \
    }                                                                     \
    for (; e < end; ++e) add8(acc, g4[(size_t)GETC(e) * 16]);
    if (staged) {
#define CL(i) scol[(i) - eBase]
        GLOOP128(CL)
#undef CL
    } else {
#define CG(i) col[i]
        GLOOP128(CG)
#undef CG
    }
#undef GLOOP128

    if (valid) {
        const float dr = dinv[r];
        __half2 hp[4] = {__floats2half2_rn(acc[0] * dr, acc[1] * dr),
                         __floats2half2_rn(acc[2] * dr, acc[3] * dr),
                         __floats2half2_rn(acc[4] * dr, acc[5] * dr),
                         __floats2half2_rn(acc[6] * dr, acc[7] * dr)};
        *(uint4*)(out + (size_t)r * 128 + half * 64 + sub * 8) = *(uint4*)hp;
    }
}

// ---------------------------------------------------------------------------

extern "C" void kernel_launch(void* const* d_in, const int* in_sizes, int n_in,
                              void* d_out, int out_size, void* d_ws, size_t ws_size,
                              hipStream_t stream) {
    const float* x  = (const float*)d_in[0];
    const int*   ei = (const int*)d_in[1];
    const float* W1 = (const float*)d_in[2];
    const float* b1 = (const float*)d_in[3];
    const float* W2 = (const float*)d_in[4];
    const float* b2 = (const float*)d_in[5];
    const float* W3 = (const float*)d_in[6];
    const float* b3 = (const float*)d_in[7];
    float* out = (float*)d_out;

    const int N = in_sizes[0] / 64;   // 100000
    const int E = in_sizes[1] / 2;    // 1600000
    const int* src = ei;
    const int* dst = ei + E;
    const int NBUCK = (N + BNODES - 1) >> BSHIFT;  // 391

    char* p = (char*)d_ws;
    auto carve = [&](size_t bytes) {
        void* q = p;
        p += (bytes + 255) & ~(size_t)255;
        return q;
    };
    int*    rowptr    = (int*)carve((size_t)(N + 1) * sizeof(int));
    int*    col       = (int*)carve((size_t)E * sizeof(int));
    float*  dinv      = (float*)carve((size_t)N * sizeof(float));
    int*    bucketCnt = (int*)carve(NBUCK_MAX * sizeof(int));
    __half* xg        = (__half*)carve((size_t)N * 64 * sizeof(__half));
    __half* Wt1       = (__half*)carve(64 * 128 * sizeof(__half));
    __half* Wt2       = (__half*)carve(128 * 128 * sizeof(__half));
    __half* Wt3       = (__half*)carve(128 * 64 * sizeof(__half));
    __half* FA        = (__half*)carve((size_t)N * 128 * sizeof(__half));
    __half* FB        = (__half*)carve((size_t)N * 128 * sizeof(__half));
    int*    ePack2    = (int*)FB;  // 8MB scratch; consumed by build_kernel
                                   // before fused gemm1 writes FB

    const int AB64  = (N + 31) / 32;
    const int AB128 = (N + 31) / 32;  // 32 rows/block per half-pass
    const int GBM = (N + 63) / 64;
    const int SB = (E + CHUNK - 1) / CHUNK;

    // --- CSR build (2 kernels; W-transpose + xg-prep fused in) ---
    hipMemsetAsync(bucketCnt, 0, NBUCK_MAX * sizeof(int), stream);
    bucket_scatter_kernel<<<SB + 128, THREADS, 0, stream>>>(
        src, dst, bucketCnt, ePack2, E, NBUCK, SB, W1, Wt1, W2, Wt2, W3, Wt3);
    build_kernel<<<NBUCK, THREADS, 0, stream>>>(
        ePack2, bucketCnt, rowptr, dinv, col, x, xg, N, NBUCK);

    // --- Layer 1 (FUSED): g1 = dinv*celu(Agg(xg)@W1+b1) -> FB ---
    agg_gemm_kernel<64, 128><<<GBM, THREADS, 0, stream>>>(
        xg, rowptr, col, dinv, b1, Wt1, FB, N);

    // --- Layer 2a: s2 = Agg(g1), two half dispatches (R19 diagnostic) -> FA ---
    agg128g_kernel<<<AB128, THREADS, 0, stream>>>(FB, rowptr, col, dinv, FA, N, 0);
    agg128g_kernel<<<AB128, THREADS, 0, stream>>>(FB, rowptr, col, dinv, FA, N, 1);

    // --- Layers 2b+3a (FUSED): g3 = dinv*(celu(s2@W2+b2)@W3) -> FB ---
    gemm23_kernel<<<GBM, THREADS, 0, stream>>>(FA, Wt2, b2, Wt3, dinv, FB, N);

    // --- Layer 3b: out = celu(Agg(g3) + b3) ---
    agg64g_kernel<true, false><<<AB64, THREADS, 0, stream>>>(FB, rowptr, col, dinv, b3, out, N);
}

// Round 11
// 287.357 us; speedup vs baseline: 1.0383x; 1.0383x over previous
//
#include <hip/hip_runtime.h>
#include <hip/hip_fp16.h>
#include <math.h>

// ---------------------------------------------------------------------------
// 3-layer GCN. R2: bucketed CSR build. R3: fp16 gathers. R4: LDS-only CSR.
// R5: MFMA dense transforms, fp16 buffers. R6: pre-scaled g. R7: oct-per-row
// aggs. R8: unroll-4 gathers, fused prep. R9: layer-2 agg split into two
// half-feature passes. R10 (REVERTED): deep pipeline + broad nt hints.
// R11: LDS col staging in aggs; agg128 58.5->55.3us, FETCH 175->164MB.
// R12-R14 (REVERTED): per-row neighbor sort — build cost swamped ~2% agg gain.
// R15: hist+scan folded away; 317->306us. R16: GEMM coalesced epilogue +
// prep fused into build/scatter. R17: layer-1 agg fused into gemm1 (294.8).
// R18: gemm2+gemm3 fused, a2 LDS-only (292.7).
// R19 (diagnostic): agg128 half-split surfaced agg_gemm: 48us, OCCUPANCY 30%
//      (28.7KB LDS -> 5 blocks/CU = 20 waves), BW 2.27TB/s vs agg128's 3.5 at
//      68% occ — fused layer-1's gather phase is concurrency-starved.
// R20: agg_gemm restructured for occupancy: 32 rows/block (grid 3125, one
//      row per oct — no serialized 2-row loop), LDS 28.7->21.3KB via
//      unpadded slot-XOR-swizzled Ws (16KB, conflict-spread reads) unioned
//      with scol + epilogue buffer; sX 32x72. 7 blocks/CU = 28 waves.
//      MFMA: 4 waves = rowTile x colHalf, NT=4. agg128 back to R18
//      single-dispatch two-half grid (split cost ~5.6us).
// ---------------------------------------------------------------------------

#define THREADS 256
#define BSHIFT 8               // nodes per bucket = 256
#define BNODES (1 << BSHIFT)
#define NBUCK_MAX 512
#define EPT 16
#define CHUNK (THREADS * EPT)
#define COLCAP 4096            // LDS col slice per agg block
#define SLOTCAP 5120           // slots per bucket (avg 4096, sigma 64)

typedef _Float16 half8 __attribute__((ext_vector_type(8)));
typedef float floatx4 __attribute__((ext_vector_type(4)));

__device__ __forceinline__ float celu1(float v) {
    return v > 0.0f ? v : expm1f(v);
}

__device__ __forceinline__ void add8(float* acc, uint4 u) {
    const __half2* h2 = (const __half2*)&u;
    float2 f;
    f = __half22float2(h2[0]); acc[0] += f.x; acc[1] += f.y;
    f = __half22float2(h2[1]); acc[2] += f.x; acc[3] += f.y;
    f = __half22float2(h2[2]); acc[4] += f.x; acc[5] += f.y;
    f = __half22float2(h2[3]); acc[6] += f.x; acc[7] += f.y;
}

// ---- CSR build: slotted counting scatter (+W transpose riders) ------------

// packed edge record: (dst & (BNODES-1)) << 20 | src   (valid: N < 2^20)
__global__ __launch_bounds__(THREADS) void bucket_scatter_kernel(
    const int* __restrict__ src, const int* __restrict__ dst,
    int* __restrict__ bucketCnt, int* __restrict__ ePack2, int E, int NBUCK,
    int SB,
    const float* __restrict__ W1, __half* __restrict__ Wt1,
    const float* __restrict__ W2, __half* __restrict__ Wt2,
    const float* __restrict__ W3, __half* __restrict__ Wt3) {
    if (blockIdx.x >= SB) {   // block-uniform branch: W-transpose riders
        int b = blockIdx.x - SB;
        const float* W; __half* Wt; int K, F;
        if (b < 32)      { W = W1; Wt = Wt1; K = 64;  F = 128; }
        else if (b < 96) { W = W2; Wt = Wt2; K = 128; F = 128; b -= 32; }
        else             { W = W3; Wt = Wt3; K = 128; F = 64;  b -= 96; }
        int i = b * THREADS + threadIdx.x;
        if (i < K * F) {
            int k = i / F, f = i % F;
            Wt[f * K + k] = __float2half(W[i]);
        }
        return;
    }
    __shared__ int lcnt[NBUCK_MAX];
    __shared__ int lbase[NBUCK_MAX];
    for (int i = threadIdx.x; i < NBUCK; i += THREADS) lcnt[i] = 0;
    __syncthreads();
    const int base = blockIdx.x * CHUNK;
    int bk[EPT], rk[EPT], pk[EPT];
#pragma unroll
    for (int i = 0; i < EPT; ++i) {
        int e = base + i * THREADS + threadIdx.x;
        if (e < E) {
            int d = dst[e];
            pk[i] = ((d & (BNODES - 1)) << 20) | src[e];
            bk[i] = d >> BSHIFT;
            rk[i] = atomicAdd(&lcnt[bk[i]], 1);
        } else {
            bk[i] = -1;
        }
    }
    __syncthreads();
    for (int i = threadIdx.x; i < NBUCK; i += THREADS)
        if (lcnt[i]) lbase[i] = atomicAdd(&bucketCnt[i], lcnt[i]);
    __syncthreads();
#pragma unroll
    for (int i = 0; i < EPT; ++i) {
        if (bk[i] >= 0) {
            int slot = lbase[bk[i]] + rk[i];
            if (slot < SLOTCAP) ePack2[bk[i] * SLOTCAP + slot] = pk[i];
        }
    }
}

// one block per bucket: in-block bucket prefix -> LDS hist -> LDS scan ->
// rowptr/dinv/col -> fused xg = dinv*x fp16 conversion for this bucket's rows.
__global__ __launch_bounds__(THREADS) void build_kernel(
    const int* __restrict__ ePack2, const int* __restrict__ bucketCnt,
    int* __restrict__ rowptr, float* __restrict__ dinv,
    int* __restrict__ col, const float* __restrict__ x,
    __half* __restrict__ xg, int N, int NBUCK) {
    __shared__ int hist[BNODES];
    __shared__ int scn[BNODES];
    __shared__ int ps[2 * BNODES];
    __shared__ float dinvS[BNODES];
    const int tid = threadIdx.x;
    const int b = blockIdx.x;

    // exclusive prefix over bucketCnt[0..NBUCK) (NBUCK <= 512)
    ps[tid] = (tid < NBUCK) ? bucketCnt[tid] : 0;
    ps[tid + 256] = (tid + 256 < NBUCK) ? bucketCnt[tid + 256] : 0;
    __syncthreads();
    for (int o = 1; o < 512; o <<= 1) {
        int a = (tid >= o) ? ps[tid - o] : 0;
        int c = ps[tid + 256 - o];           // tid+256 >= o always (o <= 256)
        __syncthreads();
        if (tid >= o) ps[tid] += a;
        ps[tid + 256] += c;
        __syncthreads();
    }
    const int cntb = bucketCnt[b];
    const int off = ps[b] - cntb;            // exclusive prefix
    if (b == NBUCK - 1 && tid == 0) rowptr[N] = ps[NBUCK - 1];
    const int base = b * SLOTCAP;

    hist[tid] = 0;
    __syncthreads();
    for (int e = tid; e < cntb; e += THREADS)
        atomicAdd(&hist[((unsigned)ePack2[base + e]) >> 20], 1);
    __syncthreads();
    int deg = hist[tid];
    scn[tid] = deg;
    __syncthreads();
    for (int o = 1; o < BNODES; o <<= 1) {
        int t = 0;
        if (tid >= o) t = scn[tid - o];
        __syncthreads();
        if (tid >= o) scn[tid] += t;
        __syncthreads();
    }
    const int ex = off + scn[tid] - deg;
    const int node = (b << BSHIFT) + tid;
    float dv = rsqrtf((float)deg + 1.0f);    // +1 self-loop
    dinvS[tid] = dv;
    if (node < N) {
        rowptr[node] = ex;
        dinv[node] = dv;
    }
    scn[tid] = ex;
    __syncthreads();
    for (int e = tid; e < cntb; e += THREADS) {
        int p = ePack2[base + e];
        int pos = atomicAdd(&scn[((unsigned)p) >> 20], 1);
        col[pos] = p & 0xFFFFF;   // plain store: col re-read by aggs soon
    }

    // fused prep: xg rows of this bucket (16B units, block-strided, coalesced)
    const int rowBase = b << BSHIFT;
    int nrows = N - rowBase;
    if (nrows > BNODES) nrows = BNODES;
    if (nrows > 0) {
        const int umax = nrows * 8;          // 8 x 16B units per 64-feat row
        const floatx4* x4 = (const floatx4*)x;
        uint4* xg4 = (uint4*)xg;
        const size_t gbase = (size_t)rowBase * 8;
        for (int u = tid; u < umax; u += THREADS) {
            float d = dinvS[u >> 3];
            size_t gi = gbase + u;
            floatx4 a = __builtin_nontemporal_load(x4 + gi * 2);  // x never re-read
            floatx4 c = __builtin_nontemporal_load(x4 + gi * 2 + 1);
            __half2 h[4] = {__floats2half2_rn(a.x * d, a.y * d), __floats2half2_rn(a.z * d, a.w * d),
                            __floats2half2_rn(c.x * d, c.y * d), __floats2half2_rn(c.z * d, c.w * d)};
            xg4[gi] = *(uint4*)h;
        }
    }
}

// ---- FUSED layer-1, 32 rows/block (R20): agg(xg) -> LDS -> MFMA -> out ----
// LDS ~21.3KB -> 7 blocks/CU (28 waves), vs R17's 28.7KB/5 blocks.
// Phase1: 32 octs, ONE row each. Phase2: Ws loaded UNPADDED with slot-XOR
// swizzle (slot^=(row&7)) over the dead scol slice. Phase3: 4 waves =
// (rowTile=w>>1) x (colHalf=w&1), NT=4. Epilogue into same union buffer.

__global__ __launch_bounds__(THREADS) void agg_gemm_kernel(
    const __half* __restrict__ g, const int* __restrict__ rowptr,
    const int* __restrict__ col, const float* __restrict__ dinv,
    const float* __restrict__ bias, const __half* __restrict__ Wt,
    __half* __restrict__ outh, int N) {
    constexpr int K = 64, F = 128;
    constexpr int KP = K + 8;            // sX row stride (halves)
    constexpr int EPI = F + 8;           // epilogue row stride (halves)
    __shared__ __half uni[8192];         // 16KB: scol -> Ws(swz) -> epi(32xEPI)
    __shared__ __half sX[32 * KP];       // 4608B aggregated A tile
    __shared__ int srp[33];
    __shared__ float dinvS[32];
    int* scol = (int*)uni;
    constexpr int SCCAP = 4096;          // int capacity of uni

    const int tid = threadIdx.x;
    const int lane = tid & 63, wave = tid >> 6;
    const int oct = lane >> 3, sub = lane & 7;
    const int r0 = blockIdx.x * 32;
    const int lr = wave * 8 + oct;       // 0..31: one row per oct
    const int r = r0 + lr;

    if (tid < 33) {
        int rr = r0 + tid;
        srp[tid] = rowptr[rr > N ? N : rr];
    }
    if (tid >= 64 && tid < 96) {
        int rr = r0 + (tid - 64);
        dinvS[tid - 64] = (rr < N) ? dinv[rr] : 0.f;
    }
    __syncthreads();
    const int eBase = srp[0], eEnd = srp[32];
    const int cnt = eEnd - eBase;
    const bool staged = (cnt <= SCCAP);
    if (staged) {
        for (int i = tid; i < cnt; i += THREADS) scol[i] = col[eBase + i];
    }
    __syncthreads();

    // ---- phase 1: gather ----
    const uint4* __restrict__ g4 = (const uint4*)g + sub;  // 8 uint4 per row
    const bool valid = (r < N);
    const int start = srp[lr], end = srp[lr + 1];
    float acc[8] = {0.f, 0.f, 0.f, 0.f, 0.f, 0.f, 0.f, 0.f};
    if (valid) add8(acc, g4[(size_t)r * 8]);   // self-loop
    int e = start;
    if (staged) {
        for (; e + 4 <= end; e += 4) {
            int c0 = scol[e - eBase], c1 = scol[e + 1 - eBase];
            int c2 = scol[e + 2 - eBase], c3 = scol[e + 3 - eBase];
            uint4 u0 = g4[(size_t)c0 * 8];
            uint4 u1 = g4[(size_t)c1 * 8];
            uint4 u2 = g4[(size_t)c2 * 8];
            uint4 u3 = g4[(size_t)c3 * 8];
            add8(acc, u0); add8(acc, u1); add8(acc, u2); add8(acc, u3);
        }
        for (; e < end; ++e) add8(acc, g4[(size_t)scol[e - eBase] * 8]);
    } else {
        for (; e + 4 <= end; e += 4) {
            int c0 = col[e], c1 = col[e + 1], c2 = col[e + 2], c3 = col[e + 3];
            uint4 u0 = g4[(size_t)c0 * 8];
            uint4 u1 = g4[(size_t)c1 * 8];
            uint4 u2 = g4[(size_t)c2 * 8];
            uint4 u3 = g4[(size_t)c3 * 8];
            add8(acc, u0); add8(acc, u1); add8(acc, u2); add8(acc, u3);
        }
        for (; e < end; ++e) add8(acc, g4[(size_t)col[e] * 8]);
    }
    {
        const float dr = dinvS[lr];
        __half2 hp[4] = {__floats2half2_rn(acc[0] * dr, acc[1] * dr),
                         __floats2half2_rn(acc[2] * dr, acc[3] * dr),
                         __floats2half2_rn(acc[4] * dr, acc[5] * dr),
                         __floats2half2_rn(acc[6] * dr, acc[7] * dr)};
        *(uint4*)&sX[lr * KP + sub * 8] = *(uint4*)hp;
    }
    __syncthreads();

    // ---- phase 2: Ws (unpadded + slot-XOR swizzle) over dead scol ----
    for (int i = tid; i < F * K / 8; i += THREADS) {   // 1024 uint4
        int f = i >> 3, kg = i & 7;
        *(uint4*)&uni[f * 64 + ((kg ^ (f & 7)) << 3)] = ((const uint4*)Wt)[i];
    }
    __syncthreads();

    // ---- phase 3: MFMA (4 waves: rowTile x colHalf, NT=4) ----
    const int q = lane >> 4, mn = lane & 15;
    const int rowTile = wave >> 1, colHalf = wave & 1;
    const int lrowA = rowTile * 16 + mn;
    floatx4 acc2[4];
#pragma unroll
    for (int t = 0; t < 4; ++t) acc2[t] = {0.f, 0.f, 0.f, 0.f};
#pragma unroll
    for (int k0 = 0; k0 < K; k0 += 32) {
        half8 a = *(const half8*)&sX[lrowA * KP + k0 + q * 8];
        const int slot = (k0 >> 3) + q;
#pragma unroll
        for (int t = 0; t < 4; ++t) {
            const int brow = colHalf * 64 + t * 16 + mn;
            half8 b = *(const half8*)&uni[brow * 64 + ((slot ^ (brow & 7)) << 3)];
            acc2[t] = __builtin_amdgcn_mfma_f32_16x16x32_f16(a, b, acc2[t], 0, 0, 0);
        }
    }

    // D: reg i <-> local row = rowTile*16 + q*4 + i, col = colHalf*64 + t*16+mn
    const int lrow0 = rowTile * 16 + q * 4;
    float dv[4];
#pragma unroll
    for (int i = 0; i < 4; ++i) dv[i] = dinvS[lrow0 + i];
    __syncthreads();   // all waves done reading uni(Ws) + sX
#pragma unroll
    for (int t = 0; t < 4; ++t) {
        const int coln = colHalf * 64 + t * 16 + mn;
        const float bv = bias[coln];
#pragma unroll
        for (int i = 0; i < 4; ++i) {
            float v = celu1(acc2[t][i] + bv) * dv[i];   // ACT + SCALE (layer 1)
            uni[(lrow0 + i) * EPI + coln] = __float2half(v);
        }
    }
    __syncthreads();
    // coalesced store: 32 rows x 16 uint4/row
    uint4* out4 = (uint4*)outh;
    for (int idx = tid; idx < 32 * 16; idx += THREADS) {
        int row = idx >> 4, chunk = idx & 15;
        int rr = r0 + row;
        if (rr < N) out4[(size_t)rr * 16 + chunk] = *(uint4*)&uni[row * EPI + chunk * 8];
    }
}

// ---- FUSED layers 2b+3a: g3 = dinv*(celu(s2@W2+b2)@W3) --------------------
// Per 64-row block: K-loop-1 (W2 in WsA, s2 nt-loaded) -> a2 into sX (LDS
// only, never global) -> W3 over dead WsA -> K-loop-2 (A = own-wave a2 rows)
// -> dinv scale -> coalesced fp16 store. Kills the 51.2MB a2 roundtrip.

__global__ __launch_bounds__(THREADS) void gemm23_kernel(
    const __half* __restrict__ X,      // s2 (FA), N x 128
    const __half* __restrict__ Wt2,    // [f][k] 128x128
    const float* __restrict__ b2,
    const __half* __restrict__ Wt3,    // [f][k] 64x128
    const float* __restrict__ dinv,
    __half* __restrict__ outh,         // g3 (FB), N x 64
    int N) {
    constexpr int K = 128;
    constexpr int KP = K + 8;          // 136
    constexpr int F2 = 128, NT2 = F2 / 16;
    constexpr int F3 = 64,  NT3 = F3 / 16;
    constexpr int FP3 = F3 + 8;        // 72 (epilogue stride; 64*FP3 < 64*KP)
    __shared__ __half WsA[F2 * KP];    // W2t, then W3t (reuse)
    __shared__ __half sX[64 * KP];     // a2 tile; reused as epilogue buffer
    __shared__ float dinvS[64];

    const int tid = threadIdx.x;
    const int wave = tid >> 6, lane = tid & 63;
    const int q = lane >> 4, mn = lane & 15;
    const int r0 = blockIdx.x * 64;

    for (int i = tid; i < F2 * K / 8; i += THREADS) {
        int f = i / (K / 8), kg = i % (K / 8);
        *(uint4*)&WsA[f * KP + kg * 8] = ((const uint4*)Wt2)[i];
    }
    if (tid < 64) {
        int rr = r0 + tid;
        dinvS[tid] = (rr < N) ? dinv[rr] : 0.f;
    }
    __syncthreads();

    int arow = r0 + wave * 16 + mn;
    if (arow >= N) arow = N - 1;       // clamp; garbage rows masked on store

    // ---- K-loop 1: acc1 = s2 @ W2 ----
    floatx4 acc1[NT2];
#pragma unroll
    for (int t = 0; t < NT2; ++t) acc1[t] = {0.f, 0.f, 0.f, 0.f};
    const __half* xp = X + (size_t)arow * K + q * 8;
#pragma unroll
    for (int k0 = 0; k0 < K; k0 += 32) {
        half8 a = __builtin_nontemporal_load((const half8*)(xp + k0));  // s2 dead after
#pragma unroll
        for (int t = 0; t < NT2; ++t) {
            half8 b = *(const half8*)&WsA[(t * 16 + mn) * KP + k0 + q * 8];
            acc1[t] = __builtin_amdgcn_mfma_f32_16x16x32_f16(a, b, acc1[t], 0, 0, 0);
        }
    }

    // ---- epilogue 1: a2 = celu(acc1 + b2) -> sX (own-wave rows) ----
    const int lrow0 = wave * 16 + q * 4;
#pragma unroll
    for (int t = 0; t < NT2; ++t) {
        const int coln = t * 16 + mn;
        const float bv = b2[coln];
#pragma unroll
        for (int i = 0; i < 4; ++i)
            sX[(lrow0 + i) * KP + coln] = __float2half(celu1(acc1[t][i] + bv));
    }
    __syncthreads();   // sX complete; WsA dead (all waves past K-loop 1)

    // ---- load W3t over WsA ----
    for (int i = tid; i < F3 * K / 8; i += THREADS) {
        int f = i / (K / 8), kg = i % (K / 8);
        *(uint4*)&WsA[f * KP + kg * 8] = ((const uint4*)Wt3)[i];
    }
    __syncthreads();

    // ---- K-loop 2: acc2 = a2 @ W3 (A = own-wave sX rows) ----
    floatx4 acc2[NT3];
#pragma unroll
    for (int t = 0; t < NT3; ++t) acc2[t] = {0.f, 0.f, 0.f, 0.f};
    const int lrowA = wave * 16 + mn;
#pragma unroll
    for (int k0 = 0; k0 < K; k0 += 32) {
        half8 a = *(const half8*)&sX[lrowA * KP + k0 + q * 8];
#pragma unroll
        for (int t = 0; t < NT3; ++t) {
            half8 b = *(const half8*)&WsA[(t * 16 + mn) * KP + k0 + q * 8];
            acc2[t] = __builtin_amdgcn_mfma_f32_16x16x32_f16(a, b, acc2[t], 0, 0, 0);
        }
    }

    float dv[4];
#pragma unroll
    for (int i = 0; i < 4; ++i) dv[i] = dinvS[lrow0 + i];
    __syncthreads();   // ALL waves done reading sX before epilogue overwrite
#pragma unroll
    for (int t = 0; t < NT3; ++t) {
        const int coln = t * 16 + mn;
#pragma unroll
        for (int i = 0; i < 4; ++i)
            sX[(lrow0 + i) * FP3 + coln] = __float2half(acc2[t][i] * dv[i]);
    }
    __syncthreads();
    // coalesced store: 64 rows x 64 halves
    constexpr int CPR = F3 / 8;
    uint4* out4 = (uint4*)outh;
    for (int idx = tid; idx < 64 * CPR; idx += THREADS) {
        int row = idx / CPR, chunk = idx % CPR;
        int r = r0 + row;
        if (r < N) out4[(size_t)r * CPR + chunk] = *(uint4*)&sX[row * FP3 + chunk * 8];
    }
}

// ---- Aggregation F=64: oct (8 lanes) per row, LDS-staged col --------------

template <bool ACT, bool OUTH>
__global__ __launch_bounds__(THREADS) void agg64g_kernel(
    const __half* __restrict__ g, const int* __restrict__ rowptr,
    const int* __restrict__ col, const float* __restrict__ dinv,
    const float* __restrict__ bias, void* __restrict__ outv, int N) {
    __shared__ int scol[COLCAP];
    __shared__ int srp[33];
    const int tid = threadIdx.x;
    const int lane = tid & 63, wave = tid >> 6;
    const int oct = lane >> 3, sub = lane & 7;
    const int r0 = blockIdx.x * 32;
    const int lr = wave * 8 + oct;
    const int r = r0 + lr;

    if (tid < 33) {
        int rr = r0 + tid;
        srp[tid] = rowptr[rr > N ? N : rr];
    }
    __syncthreads();
    const int eBase = srp[0], eEnd = srp[32];
    const int cnt = eEnd - eBase;
    const bool staged = (cnt <= COLCAP);
    if (staged) {
        for (int i = tid; i < cnt; i += THREADS) scol[i] = col[eBase + i];
    }
    __syncthreads();

    const uint4* __restrict__ g4 = (const uint4*)g + sub;  // 8 uint4 per row
    const bool valid = (r < N);
    int start = srp[lr], end = srp[lr + 1];

    float acc[8] = {0.f, 0.f, 0.f, 0.f, 0.f, 0.f, 0.f, 0.f};
    if (valid) add8(acc, g4[(size_t)r * 8]);  // self-loop

    int e = start;
#define GLOOP64(GETC)                                                     \
    for (; e + 4 <= end; e += 4) {                                        \
        int c0 = GETC(e), c1 = GETC(e + 1), c2 = GETC(e + 2), c3 = GETC(e + 3); \
        uint4 u0 = g4[(size_t)c0 * 8];                                    \
        uint4 u1 = g4[(size_t)c1 * 8];                                    \
        uint4 u2 = g4[(size_t)c2 * 8];                                    \
        uint4 u3 = g4[(size_t)c3 * 8];                                    \
        add8(acc, u0); add8(acc, u1); add8(acc, u2); add8(acc, u3);       \
    }                                                                     \
    for (; e < end; ++e) add8(acc, g4[(size_t)GETC(e) * 8]);
    if (staged) {
#define CL(i) scol[(i) - eBase]
        GLOOP64(CL)
#undef CL
    } else {
#define CG(i) col[i]
        GLOOP64(CG)
#undef CG
    }
#undef GLOOP64

    if (valid) {
        const float dr = dinv[r];
        float res[8];
#pragma unroll
        for (int k = 0; k < 8; ++k) res[k] = acc[k] * dr;
        if constexpr (ACT) {
            const float* bp = bias + sub * 8;
#pragma unroll
            for (int k = 0; k < 8; ++k) res[k] = celu1(res[k] + bp[k]);
        }
        if constexpr (OUTH) {
            __half2 hp[4] = {__floats2half2_rn(res[0], res[1]), __floats2half2_rn(res[2], res[3]),
                             __floats2half2_rn(res[4], res[5]), __floats2half2_rn(res[6], res[7])};
            *(uint4*)((__half*)outv + (size_t)r * 64 + sub * 8) = *(uint4*)hp;
        } else {
            // final layer: out never re-read -> nt stores keep table in L2
            float* o = (float*)outv + (size_t)r * 64 + sub * 8;
            floatx4 o0 = {res[0], res[1], res[2], res[3]};
            floatx4 o1 = {res[4], res[5], res[6], res[7]};
            __builtin_nontemporal_store(o0, (floatx4*)o);
            __builtin_nontemporal_store(o1, (floatx4*)o + 1);
        }
    }
}

// ---- Aggregation F=128, two phase-synchronous half-feature passes ---------
// 8-lane oct per (row, half): pass working set 12.8 MB for L2 hit rate.
// blockIdx >= NB selects the upper feature half.

__global__ __launch_bounds__(THREADS) void agg128g_kernel(
    const __half* __restrict__ g, const int* __restrict__ rowptr,
    const int* __restrict__ col, const float* __restrict__ dinv,
    __half* __restrict__ out, int N, int NB) {
    __shared__ int scol[COLCAP];
    __shared__ int srp[33];
    const int tid = threadIdx.x;
    const int lane = tid & 63, wave = tid >> 6;
    const int oct = lane >> 3, sub = lane & 7;
    int bx = blockIdx.x;
    int half = 0;
    if (bx >= NB) { half = 1; bx -= NB; }
    const int r0 = bx * 32;
    const int lr = wave * 8 + oct;
    const int r = r0 + lr;

    if (tid < 33) {
        int rr = r0 + tid;
        srp[tid] = rowptr[rr > N ? N : rr];
    }
    __syncthreads();
    const int eBase = srp[0], eEnd = srp[32];
    const int cnt = eEnd - eBase;
    const bool staged = (cnt <= COLCAP);
    if (staged) {
        for (int i = tid; i < cnt; i += THREADS) scol[i] = col[eBase + i];
    }
    __syncthreads();

    // pre-offset by feature half + sub; row stride = 16 uint4 (128 halves)
    const uint4* __restrict__ g4 = (const uint4*)g + half * 8 + sub;
    const bool valid = (r < N);
    int start = srp[lr], end = srp[lr + 1];

    float acc[8] = {0.f, 0.f, 0.f, 0.f, 0.f, 0.f, 0.f, 0.f};
    if (valid) add8(acc, g4[(size_t)r * 16]);  // self-loop

    int e = start;
#define GLOOP128(GETC)                                                    \
    for (; e + 4 <= end; e += 4) {                                        \
        int c0 = GETC(e), c1 = GETC(e + 1), c2 = GETC(e + 2), c3 = GETC(e + 3); \
        uint4 u0 = g4[(size_t)c0 * 16];                                   \
        uint4 u1 = g4[(size_t)c1 * 16];                                   \
        uint4 u2 = g4[(size_t)c2 * 16];                                   \
        uint4 u3 = g4[(size_t)c3 * 16];                                   \
        add8(acc, u0); add8(acc, u1); add8(acc, u2); add8(acc, u3);       \
    }                                                                     \
    for (; e < end; ++e) add8(acc, g4[(size_t)GETC(e) * 16]);
    if (staged) {
#define CL(i) scol[(i) - eBase]
        GLOOP128(CL)
#undef CL
    } else {
#define CG(i) col[i]
        GLOOP128(CG)
#undef CG
    }
#undef GLOOP128

    if (valid) {
        const float dr = dinv[r];
        __half2 hp[4] = {__floats2half2_rn(acc[0] * dr, acc[1] * dr),
                         __floats2half2_rn(acc[2] * dr, acc[3] * dr),
                         __floats2half2_rn(acc[4] * dr, acc[5] * dr),
                         __floats2half2_rn(acc[6] * dr, acc[7] * dr)};
        *(uint4*)(out + (size_t)r * 128 + half * 64 + sub * 8) = *(uint4*)hp;
    }
}

// ---------------------------------------------------------------------------

extern "C" void kernel_launch(void* const* d_in, const int* in_sizes, int n_in,
                              void* d_out, int out_size, void* d_ws, size_t ws_size,
                              hipStream_t stream) {
    const float* x  = (const float*)d_in[0];
    const int*   ei = (const int*)d_in[1];
    const float* W1 = (const float*)d_in[2];
    const float* b1 = (const float*)d_in[3];
    const float* W2 = (const float*)d_in[4];
    const float* b2 = (const float*)d_in[5];
    const float* W3 = (const float*)d_in[6];
    const float* b3 = (const float*)d_in[7];
    float* out = (float*)d_out;

    const int N = in_sizes[0] / 64;   // 100000
    const int E = in_sizes[1] / 2;    // 1600000
    const int* src = ei;
    const int* dst = ei + E;
    const int NBUCK = (N + BNODES - 1) >> BSHIFT;  // 391

    char* p = (char*)d_ws;
    auto carve = [&](size_t bytes) {
        void* q = p;
        p += (bytes + 255) & ~(size_t)255;
        return q;
    };
    int*    rowptr    = (int*)carve((size_t)(N + 1) * sizeof(int));
    int*    col       = (int*)carve((size_t)E * sizeof(int));
    float*  dinv      = (float*)carve((size_t)N * sizeof(float));
    int*    bucketCnt = (int*)carve(NBUCK_MAX * sizeof(int));
    __half* xg        = (__half*)carve((size_t)N * 64 * sizeof(__half));
    __half* Wt1       = (__half*)carve(64 * 128 * sizeof(__half));
    __half* Wt2       = (__half*)carve(128 * 128 * sizeof(__half));
    __half* Wt3       = (__half*)carve(128 * 64 * sizeof(__half));
    __half* FA        = (__half*)carve((size_t)N * 128 * sizeof(__half));
    __half* FB        = (__half*)carve((size_t)N * 128 * sizeof(__half));
    int*    ePack2    = (int*)FB;  // 8MB scratch; consumed by build_kernel
                                   // before fused gemm1 writes FB

    const int AB64  = (N + 31) / 32;
    const int AB128 = (N + 31) / 32;  // 32 rows/block per half-pass
    const int GB32  = (N + 31) / 32;  // fused layer-1 blocks (32 rows each)
    const int GBM = (N + 63) / 64;
    const int SB = (E + CHUNK - 1) / CHUNK;

    // --- CSR build (2 kernels; W-transpose + xg-prep fused in) ---
    hipMemsetAsync(bucketCnt, 0, NBUCK_MAX * sizeof(int), stream);
    bucket_scatter_kernel<<<SB + 128, THREADS, 0, stream>>>(
        src, dst, bucketCnt, ePack2, E, NBUCK, SB, W1, Wt1, W2, Wt2, W3, Wt3);
    build_kernel<<<NBUCK, THREADS, 0, stream>>>(
        ePack2, bucketCnt, rowptr, dinv, col, x, xg, N, NBUCK);

    // --- Layer 1 (FUSED, 32 rows/block): g1 = dinv*celu(Agg(xg)@W1+b1) -> FB ---
    agg_gemm_kernel<<<GB32, THREADS, 0, stream>>>(
        xg, rowptr, col, dinv, b1, Wt1, FB, N);

    // --- Layer 2a: s2 = Agg(g1) (two phase-synchronous half passes) -> FA ---
    agg128g_kernel<<<2 * AB128, THREADS, 0, stream>>>(FB, rowptr, col, dinv, FA, N, AB128);

    // --- Layers 2b+3a (FUSED): g3 = dinv*(celu(s2@W2+b2)@W3) -> FB ---
    gemm23_kernel<<<GBM, THREADS, 0, stream>>>(FA, Wt2, b2, Wt3, dinv, FB, N);

    // --- Layer 3b: out = celu(Agg(g3) + b3) ---
    agg64g_kernel<true, false><<<AB64, THREADS, 0, stream>>>(FB, rowptr, col, dinv, b3, out, N);
}